// Round 12
// baseline (361.618 us; speedup 1.0000x reference)
//
#include <hip/hip_runtime.h>
#include <hip/hip_bf16.h>

#define BN_EPS 1e-5f
#define SLOT 64

typedef __attribute__((ext_vector_type(4))) float f32x4;
typedef __attribute__((ext_vector_type(8))) short short8;

#define GLL16(gp, lp)                                                        \
  __builtin_amdgcn_global_load_lds(                                          \
      (const __attribute__((address_space(1))) void*)(gp),                   \
      (__attribute__((address_space(3))) void*)(lp), 16, 0, 0)

__device__ __forceinline__ unsigned short f2bf(float f) {
  union { float f; unsigned int u; } v; v.f = f;
  unsigned int r = v.u + 0x7fffu + ((v.u >> 16) & 1u);
  return (unsigned short)(r >> 16);
}
__device__ __forceinline__ float bf2f(unsigned short s) {
  union { unsigned int u; float f; } v; v.u = ((unsigned int)s) << 16; return v.f;
}

// fused prologue: weight transpose+convert (4 matrices) + zero stats + zero cnt
__global__ void wconv_zero_kernel(const float* __restrict__ w0, const float* __restrict__ w1,
                                  const float* __restrict__ w2, const float* __restrict__ w3,
                                  unsigned short* __restrict__ wt,
                                  float* __restrict__ st, int* __restrict__ cnt, int N) {
  int b = blockIdx.x;
  int gid = b * 256 + threadIdx.x;
  if (gid < 2048) st[gid] = 0.f;
  if (gid < N) cnt[gid] = 0;
  int which = b >> 10;
  int idx = (b & 1023) * 256 + threadIdx.x;  // 0..262143
  const float* w = (which == 0) ? w0 : (which == 1) ? w1 : (which == 2) ? w2 : w3;
  int k = idx >> 9, j = idx & 511;
  wt[(size_t)which * 262144 + j * 512 + k] = f2bf(w[idx]);
}

// bucket fill: srcl[d*SLOT + p] = src  (no scan; Poisson(3) degrees)
__global__ void fill_kernel(const int* __restrict__ ei, int* __restrict__ cnt,
                            int* __restrict__ srcl, int E) {
  int e = blockIdx.x * blockDim.x + threadIdx.x;
  if (e < E) {
    int d = ei[E + e];
    int p = atomicAdd(&cnt[d], 1);
    if (p < SLOT) srcl[(size_t)d * SLOT + p] = ei[e];
  }
}

// ---- gather: h[i] = bf16( y(i) + sum_{j in N(i)} y(j) )
// BN=false: input f32 x, y = x.
// BN=true: input bf16 u, y = relu(u*sc+sh); sc/sh computed inline from
//          sum/sumsq/gamma/beta (finalize fused).
template<bool BN>
__global__ __launch_bounds__(256) void gather_kernel(
    const void* __restrict__ xin, const int* __restrict__ cnt,
    const int* __restrict__ srcl, const float* __restrict__ sum,
    const float* __restrict__ sumsq, const float* __restrict__ gamma,
    const float* __restrict__ beta, unsigned short* __restrict__ hout, int N)
{
  int node = blockIdx.x * 4 + (threadIdx.x >> 6);
  if (node >= N) return;
  int c = (threadIdx.x & 63) * 8;

  f32x4 sc0, sc1, sh0, sh1;
  if (BN) {
    const float inv = 1.f / (float)N;
#pragma unroll
    for (int h = 0; h < 2; ++h) {
      f32x4 sm = *(const f32x4*)&sum[c + h * 4];
      f32x4 sq = *(const f32x4*)&sumsq[c + h * 4];
      f32x4 gm = *(const f32x4*)&gamma[c + h * 4];
      f32x4 bt = *(const f32x4*)&beta[c + h * 4];
      f32x4 sc, sh;
#pragma unroll
      for (int q = 0; q < 4; ++q) {
        float mu = sm[q] * inv;
        float var = sq[q] * inv - mu * mu;
        float s = gm[q] * rsqrtf(var + BN_EPS);
        sc[q] = s;
        sh[q] = bt[q] - mu * s;
      }
      if (h == 0) { sc0 = sc; sh0 = sh; } else { sc1 = sc; sh1 = sh; }
    }
  }

#define LOADROW(IDX, V0, V1)                                                  \
  do {                                                                        \
    if (BN) {                                                                 \
      const unsigned short* rp = (const unsigned short*)xin + (size_t)(IDX) * 512 + c; \
      short8 rv = *(const short8*)rp;                                         \
      for (int q = 0; q < 4; ++q) {                                           \
        V0[q] = bf2f((unsigned short)rv[q]);                                  \
        V1[q] = bf2f((unsigned short)rv[q + 4]);                              \
      }                                                                       \
      V0 = V0 * sc0 + sh0; V1 = V1 * sc1 + sh1;                               \
      for (int q = 0; q < 4; ++q) {                                           \
        V0[q] = fmaxf(V0[q], 0.f); V1[q] = fmaxf(V1[q], 0.f);                 \
      }                                                                       \
    } else {                                                                  \
      const float* rp = (const float*)xin + (size_t)(IDX) * 512 + c;          \
      V0 = *(const f32x4*)rp; V1 = *(const f32x4*)(rp + 4);                   \
    }                                                                         \
  } while (0)

  f32x4 a0, a1;
  LOADROW(node, a0, a1);

  int degv = cnt[node];
  if (degv > SLOT) degv = SLOT;
  const int* sl = srcl + (size_t)node * SLOT;
  int p = 0;
  while (p + 2 <= degv) {
    int iA = sl[p], iB = sl[p + 1];
    f32x4 v0, v1, w0, w1;
    LOADROW(iA, v0, v1);
    LOADROW(iB, w0, w1);
    a0 += v0 + w0; a1 += v1 + w1;
    p += 2;
  }
  if (p < degv) {
    int iA = sl[p];
    f32x4 v0, v1;
    LOADROW(iA, v0, v1);
    a0 += v0; a1 += v1;
  }
#undef LOADROW

  short8 o;
  o[0] = f2bf(a0[0]); o[1] = f2bf(a0[1]); o[2] = f2bf(a0[2]); o[3] = f2bf(a0[3]);
  o[4] = f2bf(a1[0]); o[5] = f2bf(a1[1]); o[6] = f2bf(a1[2]); o[7] = f2bf(a1[3]);
  *(short8*)&hout[(size_t)node * 512 + c] = o;
}

// ---- GEMM: C[M x 512] = bf16( act(A[M x 512] @ W[512 x 512] + bias) ) ----
// Paired-K variant of the r8 winner: 128x128 tile, 4 waves (2x2), BK=32,
// FIVE-buffer LDS ring (80KB, 2 blocks/CU). Two K-tiles (32 MFMA) per
// barrier -> 8 barrier/wait events instead of 16, same 2-step prefetch
// cover. Per-wave vmcnt ledger (2 gll per STAGE):
//   prologue: stage {0,1,2}; vmcnt(2) -> tiles 0,1 done, tile 2 in flight.
//   step s (0..7): stage {2s+3, 2s+4} (s<=5) / {15} (s==6); compute tiles
//   {2s, 2s+1}; lgkmcnt(0); vmcnt(2) (s<=5, retires 2s+2,2s+3) or vmcnt(0)
//   (s==6); s_barrier (s<7). Overwritten bufs' readers retired all ds_reads
//   via lgkmcnt(0) before the previous barrier.
// Swizzle: stored col16' = col16 ^ (row&3), matching swizzled ds_read.
// STATS: per-column sum/sumsq via shfl+atomics from f32 acc (pre-rounding).
template<bool RELU, bool STATS>
__global__ __launch_bounds__(256) void gemm_kernel(
    const unsigned short* __restrict__ A, const unsigned short* __restrict__ Wt,
    const float* __restrict__ bias, unsigned short* __restrict__ Cp, int M, int nwg,
    float* __restrict__ sum, float* __restrict__ sumsq)
{
  __shared__ unsigned short S[5][2][4096];  // [buf][A|B][128 rows x 32 k] = 80KB

  const int bid = blockIdx.x;
  const int xcd = bid & 7, pos = bid >> 3;
  const int q8 = nwg >> 3, r8 = nwg & 7;
  const int base = (xcd < r8) ? xcd * (q8 + 1) : r8 * (q8 + 1) + (xcd - r8) * q8;
  const int wg = base + pos;
  const int i0 = (wg >> 2) * 128;
  const int j0 = (wg & 3) * 128;

  const int tid = threadIdx.x;
  const int lane = tid & 63;
  const int wid = tid >> 6;
  const int wr = wid >> 1, wc = wid & 1;
  const int l15 = lane & 15, lg = lane >> 4;

  const int srow = lane >> 2;
  const int scol = (lane & 3) ^ (srow & 3);
  const unsigned short* gA = A + (size_t)(i0 + srow) * 512 + scol * 8;
  const unsigned short* gB = Wt + (size_t)(j0 + srow) * 512 + scol * 8;

#define STAGE(TILE, BUF)                                                      \
  {                                                                           \
    const size_t kk = (size_t)(TILE) * 32;                                    \
    _Pragma("unroll")                                                         \
    for (int j = 0; j < 2; ++j) {                                             \
      int cch = wid * 2 + j;                                                  \
      GLL16(gA + (size_t)cch * 16 * 512 + kk, &S[BUF][0][cch * 512]);         \
      GLL16(gB + (size_t)cch * 16 * 512 + kk, &S[BUF][1][cch * 512]);         \
    }                                                                         \
  }

  const int aslot = (lg ^ (l15 & 3)) * 8;
  const int arow = (wr * 64 + l15) * 32 + aslot;
  const int brow = (wc * 64 + l15) * 32 + aslot;

  f32x4 acc[4][4];
#pragma unroll
  for (int m = 0; m < 4; ++m)
#pragma unroll
    for (int n = 0; n < 4; ++n)
      acc[m][n] = (f32x4){0.f, 0.f, 0.f, 0.f};

  // prologue: stage tiles 0,1,2; vmcnt(2) = tiles 0,1 done, tile 2 flying
  STAGE(0, 0)
  STAGE(1, 1)
  STAGE(2, 2)
  asm volatile("s_waitcnt vmcnt(2)" ::: "memory");
  __builtin_amdgcn_s_barrier();

#pragma unroll
  for (int s = 0; s < 8; ++s) {
    const int cur0 = (2 * s) % 5;
    const int cur1 = (2 * s + 1) % 5;
    if (s <= 5) {
      STAGE(2 * s + 3, (2 * s + 3) % 5)
      if (s < 6 && 2 * s + 4 <= 15) {
        STAGE(2 * s + 4, (2 * s + 4) % 5)
      }
    } else if (s == 6) {
      STAGE(15, 0)
    }

    short8 a0[4], b0[4], a1[4], b1[4];
#pragma unroll
    for (int m = 0; m < 4; ++m) {
      a0[m] = *(const short8*)&S[cur0][0][m * 512 + arow];
      a1[m] = *(const short8*)&S[cur1][0][m * 512 + arow];
    }
#pragma unroll
    for (int n = 0; n < 4; ++n) {
      b0[n] = *(const short8*)&S[cur0][1][n * 512 + brow];
      b1[n] = *(const short8*)&S[cur1][1][n * 512 + brow];
    }
    __builtin_amdgcn_s_setprio(1);
#pragma unroll
    for (int m = 0; m < 4; ++m)
#pragma unroll
      for (int n = 0; n < 4; ++n)
        acc[m][n] = __builtin_amdgcn_mfma_f32_16x16x32_bf16(a0[m], b0[n],
                                                            acc[m][n], 0, 0, 0);
#pragma unroll
    for (int m = 0; m < 4; ++m)
#pragma unroll
      for (int n = 0; n < 4; ++n)
        acc[m][n] = __builtin_amdgcn_mfma_f32_16x16x32_bf16(a1[m], b1[n],
                                                            acc[m][n], 0, 0, 0);
    __builtin_amdgcn_s_setprio(0);

    asm volatile("s_waitcnt lgkmcnt(0)" ::: "memory");
    if (s <= 5) {
      asm volatile("s_waitcnt vmcnt(2)" ::: "memory");  // tiles 2s+2,2s+3 done
    } else if (s == 6) {
      asm volatile("s_waitcnt vmcnt(0)" ::: "memory");  // tiles 14,15 done
    }
    if (s < 7) __builtin_amdgcn_s_barrier();
  }
#undef STAGE

  __syncthreads();  // protect S reuse as epilogue tile T

  unsigned short* T = (unsigned short*)S;  // [128][132] shorts (33KB <= 80KB)

#pragma unroll
  for (int n = 0; n < 4; ++n) {
    const int coll = wc * 64 + n * 16 + l15;
    const float bv = bias[j0 + coll];
    float sv = 0.f, qv = 0.f;
#pragma unroll
    for (int m = 0; m < 4; ++m) {
      const int rowl0 = wr * 64 + m * 16 + lg * 4;
#pragma unroll
      for (int q = 0; q < 4; ++q) {
        float v = acc[m][n][q] + bv;
        if (RELU) v = fmaxf(v, 0.f);
        if (STATS && (i0 + rowl0 + q) < M) { sv += v; qv += v * v; }
        T[(rowl0 + q) * 132 + coll] = f2bf(v);
      }
    }
    if (STATS) {
      sv += __shfl_xor(sv, 16); qv += __shfl_xor(qv, 16);
      sv += __shfl_xor(sv, 32); qv += __shfl_xor(qv, 32);
      if (lg == 0) {
        atomicAdd(&sum[j0 + coll], sv);
        atomicAdd(&sumsq[j0 + coll], qv);
      }
    }
  }
  __syncthreads();

  {
    const int ch = tid & 15;
    const int rbase = tid >> 4;
#pragma unroll
    for (int i = 0; i < 8; ++i) {
      int rl = rbase + i * 16;
      int gr = i0 + rl;
      if (gr < M) {
        short8 vv = *(const short8*)&T[rl * 132 + ch * 8];
        *(short8*)&Cp[(size_t)gr * 512 + j0 + ch * 8] = vv;
      }
    }
  }
}

// d_out = relu(u*sc+sh) + x  (u bf16, x/out f32); sc/sh computed inline
// from sum2/sumsq2/gamma2/beta2 (finalize fused).
__global__ void bn_res_kernel(const unsigned short* __restrict__ u,
                              const float* __restrict__ sum,
                              const float* __restrict__ sumsq,
                              const float* __restrict__ gamma,
                              const float* __restrict__ beta,
                              const float* __restrict__ x,
                              float* __restrict__ y, int n8, int M) {
  int gid = blockIdx.x * blockDim.x + threadIdx.x;
  if (gid >= n8) return;
  size_t e0 = (size_t)gid * 8;
  int c0 = (int)(e0 & 511);
  const float inv = 1.f / (float)M;
  short8 uu = *(const short8*)&u[e0];
  f32x4 x0 = *(const f32x4*)&x[e0], x1 = *(const f32x4*)&x[e0 + 4];
  f32x4 r0, r1;
#pragma unroll
  for (int h = 0; h < 2; ++h) {
    f32x4 sm = *(const f32x4*)&sum[c0 + h * 4];
    f32x4 sq = *(const f32x4*)&sumsq[c0 + h * 4];
    f32x4 gm = *(const f32x4*)&gamma[c0 + h * 4];
    f32x4 bt = *(const f32x4*)&beta[c0 + h * 4];
#pragma unroll
    for (int q = 0; q < 4; ++q) {
      float mu = sm[q] * inv;
      float var = sq[q] * inv - mu * mu;
      float s = gm[q] * rsqrtf(var + BN_EPS);
      float sh = bt[q] - mu * s;
      float uv = bf2f((unsigned short)uu[h * 4 + q]);
      float rv = fmaxf(uv * s + sh, 0.f);
      if (h == 0) r0[q] = rv + x0[q];
      else        r1[q] = rv + x1[q];
    }
  }
  *(f32x4*)&y[e0] = r0;
  *(f32x4*)&y[e0 + 4] = r1;
}

extern "C" void kernel_launch(void* const* d_in, const int* in_sizes, int n_in,
                              void* d_out, int out_size, void* d_ws, size_t ws_size,
                              hipStream_t stream) {
  const float* x   = (const float*)d_in[0];
  const int*   ei  = (const int*)d_in[1];
  const float* w1a = (const float*)d_in[2];
  const float* b1a = (const float*)d_in[3];
  const float* w1b = (const float*)d_in[4];
  const float* b1b = (const float*)d_in[5];
  const float* g1  = (const float*)d_in[6];
  const float* be1 = (const float*)d_in[7];
  const float* w2a = (const float*)d_in[8];
  const float* b2a = (const float*)d_in[9];
  const float* w2b = (const float*)d_in[10];
  const float* b2b = (const float*)d_in[11];
  const float* g2  = (const float*)d_in[12];
  const float* be2 = (const float*)d_in[13];

  const int N = in_sizes[0] / 512;
  const int E = in_sizes[1] / 2;
  const size_t ND = (size_t)N * 512;

  char* ws = (char*)d_ws;
  unsigned short* hbf = (unsigned short*)ws;              // ND bf16
  unsigned short* t1  = (unsigned short*)(ws + ND * 2);   // ND bf16
  unsigned short* u   = (unsigned short*)(ws + ND * 4);   // ND bf16
  unsigned short* wt  = (unsigned short*)(ws + ND * 6);   // 4 x 512x512 bf16
  char* p = ws + ND * 6 + (size_t)4 * 262144 * 2;
  float* st = (float*)p;                                  // 2048 f32
  float* sum1 = st,        *sq1 = st + 512;
  float* sum2 = st + 1024, *sq2 = st + 1536;
  p += 4096 * 4;
  int* cnt  = (int*)p;             p += (size_t)N * 4;
  int* srcl = (int*)p;             p += (size_t)N * SLOT * 4;

  const int n8 = (int)(ND / 8);
  const int nbE = (E + 255) / 256;
  const int nwg = ((N + 127) / 128) * 4;
  const int ggather = (N + 3) / 4;

  // fused prologue: weight convert + zero stats + zero cnt
  wconv_zero_kernel<<<4096, 256, 0, stream>>>(w1a, w1b, w2a, w2b, wt, st, cnt, N);

  // bucket-CSR build (single kernel, no scan)
  fill_kernel<<<nbE, 256, 0, stream>>>(ei, cnt, srcl, E);

  // ---- layer 1 ----
  gather_kernel<false><<<ggather, 256, 0, stream>>>(x, cnt, srcl,
                                                    nullptr, nullptr, nullptr, nullptr,
                                                    hbf, N);
  gemm_kernel<true, false><<<nwg, 256, 0, stream>>>(hbf, wt, b1a, t1, N, nwg,
                                                    nullptr, nullptr);
  gemm_kernel<false, true><<<nwg, 256, 0, stream>>>(t1, wt + 262144, b1b, u, N, nwg,
                                                    sum1, sq1);

  // ---- layer 2 (BN finalize fused into gather) ----
  gather_kernel<true><<<ggather, 256, 0, stream>>>(u, cnt, srcl,
                                                   sum1, sq1, g1, be1, hbf, N);
  gemm_kernel<true, false><<<nwg, 256, 0, stream>>>(hbf, wt + 2 * 262144, b2a, t1, N,
                                                    nwg, nullptr, nullptr);
  gemm_kernel<false, true><<<nwg, 256, 0, stream>>>(t1, wt + 3 * 262144, b2b, u, N,
                                                    nwg, sum2, sq2);
  bn_res_kernel<<<(n8 + 255) / 256, 256, 0, stream>>>(u, sum2, sq2, g2, be2,
                                                      x, (float*)d_out, n8, N);
}

// Round 13
// 341.267 us; speedup vs baseline: 1.0596x; 1.0596x over previous
//
#include <hip/hip_runtime.h>
#include <hip/hip_bf16.h>

#define BN_EPS 1e-5f
#define SLOT 64

typedef __attribute__((ext_vector_type(4))) float f32x4;
typedef __attribute__((ext_vector_type(8))) short short8;

#define GLL16(gp, lp)                                                        \
  __builtin_amdgcn_global_load_lds(                                          \
      (const __attribute__((address_space(1))) void*)(gp),                   \
      (__attribute__((address_space(3))) void*)(lp), 16, 0, 0)

__device__ __forceinline__ unsigned short f2bf(float f) {
  union { float f; unsigned int u; } v; v.f = f;
  unsigned int r = v.u + 0x7fffu + ((v.u >> 16) & 1u);
  return (unsigned short)(r >> 16);
}
__device__ __forceinline__ float bf2f(unsigned short s) {
  union { unsigned int u; float f; } v; v.u = ((unsigned int)s) << 16; return v.f;
}

// fused prologue: weight transpose+convert (4 matrices) + zero stats + zero cnt
__global__ void wconv_zero_kernel(const float* __restrict__ w0, const float* __restrict__ w1,
                                  const float* __restrict__ w2, const float* __restrict__ w3,
                                  unsigned short* __restrict__ wt,
                                  float* __restrict__ st, int* __restrict__ cnt, int N) {
  int b = blockIdx.x;
  int gid = b * 256 + threadIdx.x;
  if (gid < 2048) st[gid] = 0.f;
  if (gid < N) cnt[gid] = 0;
  int which = b >> 10;
  int idx = (b & 1023) * 256 + threadIdx.x;  // 0..262143
  const float* w = (which == 0) ? w0 : (which == 1) ? w1 : (which == 2) ? w2 : w3;
  int k = idx >> 9, j = idx & 511;
  wt[(size_t)which * 262144 + j * 512 + k] = f2bf(w[idx]);
}

// bucket fill: srcl[d*SLOT + p] = src  (no scan; Poisson(3) degrees)
__global__ void fill_kernel(const int* __restrict__ ei, int* __restrict__ cnt,
                            int* __restrict__ srcl, int E) {
  int e = blockIdx.x * blockDim.x + threadIdx.x;
  if (e < E) {
    int d = ei[E + e];
    int p = atomicAdd(&cnt[d], 1);
    if (p < SLOT) srcl[(size_t)d * SLOT + p] = ei[e];
  }
}

// ---- gather: h[i] = bf16( y(i) + sum_{j in N(i)} y(j) )
// BN=false: input f32 x, y = x.
// BN=true: input bf16 u, y = relu(u*sc+sh); sc/sh computed inline from
//          sum/sumsq/gamma/beta (finalize fused).
template<bool BN>
__global__ __launch_bounds__(256) void gather_kernel(
    const void* __restrict__ xin, const int* __restrict__ cnt,
    const int* __restrict__ srcl, const float* __restrict__ sum,
    const float* __restrict__ sumsq, const float* __restrict__ gamma,
    const float* __restrict__ beta, unsigned short* __restrict__ hout, int N)
{
  int node = blockIdx.x * 4 + (threadIdx.x >> 6);
  if (node >= N) return;
  int c = (threadIdx.x & 63) * 8;

  f32x4 sc0, sc1, sh0, sh1;
  if (BN) {
    const float inv = 1.f / (float)N;
#pragma unroll
    for (int h = 0; h < 2; ++h) {
      f32x4 sm = *(const f32x4*)&sum[c + h * 4];
      f32x4 sq = *(const f32x4*)&sumsq[c + h * 4];
      f32x4 gm = *(const f32x4*)&gamma[c + h * 4];
      f32x4 bt = *(const f32x4*)&beta[c + h * 4];
      f32x4 sc, sh;
#pragma unroll
      for (int q = 0; q < 4; ++q) {
        float mu = sm[q] * inv;
        float var = sq[q] * inv - mu * mu;
        float s = gm[q] * rsqrtf(var + BN_EPS);
        sc[q] = s;
        sh[q] = bt[q] - mu * s;
      }
      if (h == 0) { sc0 = sc; sh0 = sh; } else { sc1 = sc; sh1 = sh; }
    }
  }

#define LOADROW(IDX, V0, V1)                                                  \
  do {                                                                        \
    if (BN) {                                                                 \
      const unsigned short* rp = (const unsigned short*)xin + (size_t)(IDX) * 512 + c; \
      short8 rv = *(const short8*)rp;                                         \
      for (int q = 0; q < 4; ++q) {                                           \
        V0[q] = bf2f((unsigned short)rv[q]);                                  \
        V1[q] = bf2f((unsigned short)rv[q + 4]);                              \
      }                                                                       \
      V0 = V0 * sc0 + sh0; V1 = V1 * sc1 + sh1;                               \
      for (int q = 0; q < 4; ++q) {                                           \
        V0[q] = fmaxf(V0[q], 0.f); V1[q] = fmaxf(V1[q], 0.f);                 \
      }                                                                       \
    } else {                                                                  \
      const float* rp = (const float*)xin + (size_t)(IDX) * 512 + c;          \
      V0 = *(const f32x4*)rp; V1 = *(const f32x4*)(rp + 4);                   \
    }                                                                         \
  } while (0)

  f32x4 a0, a1;
  LOADROW(node, a0, a1);

  int degv = cnt[node];
  if (degv > SLOT) degv = SLOT;
  const int* sl = srcl + (size_t)node * SLOT;
  int p = 0;
  while (p + 2 <= degv) {
    int iA = sl[p], iB = sl[p + 1];
    f32x4 v0, v1, w0, w1;
    LOADROW(iA, v0, v1);
    LOADROW(iB, w0, w1);
    a0 += v0 + w0; a1 += v1 + w1;
    p += 2;
  }
  if (p < degv) {
    int iA = sl[p];
    f32x4 v0, v1;
    LOADROW(iA, v0, v1);
    a0 += v0; a1 += v1;
  }
#undef LOADROW

  short8 o;
  o[0] = f2bf(a0[0]); o[1] = f2bf(a0[1]); o[2] = f2bf(a0[2]); o[3] = f2bf(a0[3]);
  o[4] = f2bf(a1[0]); o[5] = f2bf(a1[1]); o[6] = f2bf(a1[2]); o[7] = f2bf(a1[3]);
  *(short8*)&hout[(size_t)node * 512 + c] = o;
}

// ---- GEMM: C[M x 512] = bf16( act(A[M x 512] @ W[512 x 512] + bias) ) ----
// r11 winner: 128x128 tile, 4 waves (2x2), BK=32, TRIPLE-buffered LDS (48KB,
// 3 blocks/CU), counted-vmcnt pipeline: stage 2 K-tiles ahead; per step
// lgkmcnt(0) + vmcnt(4) + raw s_barrier (vmcnt(0) only at kt=14). T5 setprio
// around the MFMA cluster. Swizzle: stored col16' = col16 ^ (row&3), matching
// swizzled ds_read. STATS: per-column sum/sumsq via shfl+atomics (pre-round).
template<bool RELU, bool STATS>
__global__ __launch_bounds__(256) void gemm_kernel(
    const unsigned short* __restrict__ A, const unsigned short* __restrict__ Wt,
    const float* __restrict__ bias, unsigned short* __restrict__ Cp, int M, int nwg,
    float* __restrict__ sum, float* __restrict__ sumsq)
{
  __shared__ unsigned short S[3][2][4096];  // [buf][A|B][128 rows x 32 k]

  const int bid = blockIdx.x;
  const int xcd = bid & 7, pos = bid >> 3;
  const int q8 = nwg >> 3, r8 = nwg & 7;
  const int base = (xcd < r8) ? xcd * (q8 + 1) : r8 * (q8 + 1) + (xcd - r8) * q8;
  const int wg = base + pos;
  const int i0 = (wg >> 2) * 128;
  const int j0 = (wg & 3) * 128;

  const int tid = threadIdx.x;
  const int lane = tid & 63;
  const int wid = tid >> 6;
  const int wr = wid >> 1, wc = wid & 1;
  const int l15 = lane & 15, lg = lane >> 4;

  const int srow = lane >> 2;
  const int scol = (lane & 3) ^ (srow & 3);
  const unsigned short* gA = A + (size_t)(i0 + srow) * 512 + scol * 8;
  const unsigned short* gB = Wt + (size_t)(j0 + srow) * 512 + scol * 8;

#define STAGE(TILE, BUF)                                                      \
  {                                                                           \
    const size_t kk = (size_t)(TILE) * 32;                                    \
    _Pragma("unroll")                                                         \
    for (int j = 0; j < 2; ++j) {                                             \
      int cch = wid * 2 + j;                                                  \
      GLL16(gA + (size_t)cch * 16 * 512 + kk, &S[BUF][0][cch * 512]);         \
      GLL16(gB + (size_t)cch * 16 * 512 + kk, &S[BUF][1][cch * 512]);         \
    }                                                                         \
  }

  const int aslot = (lg ^ (l15 & 3)) * 8;
  const int arow = (wr * 64 + l15) * 32 + aslot;
  const int brow = (wc * 64 + l15) * 32 + aslot;

  f32x4 acc[4][4];
#pragma unroll
  for (int m = 0; m < 4; ++m)
#pragma unroll
    for (int n = 0; n < 4; ++n)
      acc[m][n] = (f32x4){0.f, 0.f, 0.f, 0.f};

  STAGE(0, 0)
  STAGE(1, 1)
  asm volatile("s_waitcnt vmcnt(4)" ::: "memory");
  __builtin_amdgcn_s_barrier();

#pragma unroll
  for (int kt = 0; kt < 16; ++kt) {
    const int cur = kt % 3;
    if (kt < 14) {
      STAGE(kt + 2, (kt + 2) % 3)
    }

    short8 a[4], b[4];
#pragma unroll
    for (int m = 0; m < 4; ++m)
      a[m] = *(const short8*)&S[cur][0][m * 512 + arow];
#pragma unroll
    for (int n = 0; n < 4; ++n)
      b[n] = *(const short8*)&S[cur][1][n * 512 + brow];
    __builtin_amdgcn_s_setprio(1);
#pragma unroll
    for (int m = 0; m < 4; ++m)
#pragma unroll
      for (int n = 0; n < 4; ++n)
        acc[m][n] = __builtin_amdgcn_mfma_f32_16x16x32_bf16(a[m], b[n],
                                                            acc[m][n], 0, 0, 0);
    __builtin_amdgcn_s_setprio(0);

    asm volatile("s_waitcnt lgkmcnt(0)" ::: "memory");
    if (kt < 14) {
      asm volatile("s_waitcnt vmcnt(4)" ::: "memory");
    } else if (kt == 14) {
      asm volatile("s_waitcnt vmcnt(0)" ::: "memory");
    }
    if (kt < 15) __builtin_amdgcn_s_barrier();
  }
#undef STAGE

  __syncthreads();  // protect S reuse as epilogue tile T

  unsigned short* T = (unsigned short*)S;  // [128][132] shorts

#pragma unroll
  for (int n = 0; n < 4; ++n) {
    const int coll = wc * 64 + n * 16 + l15;
    const float bv = bias[j0 + coll];
    float sv = 0.f, qv = 0.f;
#pragma unroll
    for (int m = 0; m < 4; ++m) {
      const int rowl0 = wr * 64 + m * 16 + lg * 4;
#pragma unroll
      for (int q = 0; q < 4; ++q) {
        float v = acc[m][n][q] + bv;
        if (RELU) v = fmaxf(v, 0.f);
        if (STATS && (i0 + rowl0 + q) < M) { sv += v; qv += v * v; }
        T[(rowl0 + q) * 132 + coll] = f2bf(v);
      }
    }
    if (STATS) {
      sv += __shfl_xor(sv, 16); qv += __shfl_xor(qv, 16);
      sv += __shfl_xor(sv, 32); qv += __shfl_xor(qv, 32);
      if (lg == 0) {
        atomicAdd(&sum[j0 + coll], sv);
        atomicAdd(&sumsq[j0 + coll], qv);
      }
    }
  }
  __syncthreads();

  {
    const int ch = tid & 15;
    const int rbase = tid >> 4;
#pragma unroll
    for (int i = 0; i < 8; ++i) {
      int rl = rbase + i * 16;
      int gr = i0 + rl;
      if (gr < M) {
        short8 vv = *(const short8*)&T[rl * 132 + ch * 8];
        *(short8*)&Cp[(size_t)gr * 512 + j0 + ch * 8] = vv;
      }
    }
  }
}

// d_out = relu(u*sc+sh) + x  (u bf16, x/out f32); sc/sh computed inline
// from sum2/sumsq2/gamma2/beta2 (finalize fused).
__global__ void bn_res_kernel(const unsigned short* __restrict__ u,
                              const float* __restrict__ sum,
                              const float* __restrict__ sumsq,
                              const float* __restrict__ gamma,
                              const float* __restrict__ beta,
                              const float* __restrict__ x,
                              float* __restrict__ y, int n8, int M) {
  int gid = blockIdx.x * blockDim.x + threadIdx.x;
  if (gid >= n8) return;
  size_t e0 = (size_t)gid * 8;
  int c0 = (int)(e0 & 511);
  const float inv = 1.f / (float)M;
  short8 uu = *(const short8*)&u[e0];
  f32x4 x0 = *(const f32x4*)&x[e0], x1 = *(const f32x4*)&x[e0 + 4];
  f32x4 r0, r1;
#pragma unroll
  for (int h = 0; h < 2; ++h) {
    f32x4 sm = *(const f32x4*)&sum[c0 + h * 4];
    f32x4 sq = *(const f32x4*)&sumsq[c0 + h * 4];
    f32x4 gm = *(const f32x4*)&gamma[c0 + h * 4];
    f32x4 bt = *(const f32x4*)&beta[c0 + h * 4];
#pragma unroll
    for (int q = 0; q < 4; ++q) {
      float mu = sm[q] * inv;
      float var = sq[q] * inv - mu * mu;
      float s = gm[q] * rsqrtf(var + BN_EPS);
      float sh = bt[q] - mu * s;
      float uv = bf2f((unsigned short)uu[h * 4 + q]);
      float rv = fmaxf(uv * s + sh, 0.f);
      if (h == 0) r0[q] = rv + x0[q];
      else        r1[q] = rv + x1[q];
    }
  }
  *(f32x4*)&y[e0] = r0;
  *(f32x4*)&y[e0 + 4] = r1;
}

extern "C" void kernel_launch(void* const* d_in, const int* in_sizes, int n_in,
                              void* d_out, int out_size, void* d_ws, size_t ws_size,
                              hipStream_t stream) {
  const float* x   = (const float*)d_in[0];
  const int*   ei  = (const int*)d_in[1];
  const float* w1a = (const float*)d_in[2];
  const float* b1a = (const float*)d_in[3];
  const float* w1b = (const float*)d_in[4];
  const float* b1b = (const float*)d_in[5];
  const float* g1  = (const float*)d_in[6];
  const float* be1 = (const float*)d_in[7];
  const float* w2a = (const float*)d_in[8];
  const float* b2a = (const float*)d_in[9];
  const float* w2b = (const float*)d_in[10];
  const float* b2b = (const float*)d_in[11];
  const float* g2  = (const float*)d_in[12];
  const float* be2 = (const float*)d_in[13];

  const int N = in_sizes[0] / 512;
  const int E = in_sizes[1] / 2;
  const size_t ND = (size_t)N * 512;

  char* ws = (char*)d_ws;
  unsigned short* hbf = (unsigned short*)ws;              // ND bf16
  unsigned short* t1  = (unsigned short*)(ws + ND * 2);   // ND bf16
  unsigned short* u   = (unsigned short*)(ws + ND * 4);   // ND bf16
  unsigned short* wt  = (unsigned short*)(ws + ND * 6);   // 4 x 512x512 bf16
  char* p = ws + ND * 6 + (size_t)4 * 262144 * 2;
  float* st = (float*)p;                                  // 2048 f32
  float* sum1 = st,        *sq1 = st + 512;
  float* sum2 = st + 1024, *sq2 = st + 1536;
  p += 4096 * 4;
  int* cnt  = (int*)p;             p += (size_t)N * 4;
  int* srcl = (int*)p;             p += (size_t)N * SLOT * 4;

  const int n8 = (int)(ND / 8);
  const int nbE = (E + 255) / 256;
  const int nwg = ((N + 127) / 128) * 4;
  const int ggather = (N + 3) / 4;

  // fused prologue: weight convert + zero stats + zero cnt
  wconv_zero_kernel<<<4096, 256, 0, stream>>>(w1a, w1b, w2a, w2b, wt, st, cnt, N);

  // bucket-CSR build (single kernel, no scan)
  fill_kernel<<<nbE, 256, 0, stream>>>(ei, cnt, srcl, E);

  // ---- layer 1 ----
  gather_kernel<false><<<ggather, 256, 0, stream>>>(x, cnt, srcl,
                                                    nullptr, nullptr, nullptr, nullptr,
                                                    hbf, N);
  gemm_kernel<true, false><<<nwg, 256, 0, stream>>>(hbf, wt, b1a, t1, N, nwg,
                                                    nullptr, nullptr);
  gemm_kernel<false, true><<<nwg, 256, 0, stream>>>(t1, wt + 262144, b1b, u, N, nwg,
                                                    sum1, sq1);

  // ---- layer 2 (BN finalize fused into gather) ----
  gather_kernel<true><<<ggather, 256, 0, stream>>>(u, cnt, srcl,
                                                   sum1, sq1, g1, be1, hbf, N);
  gemm_kernel<true, false><<<nwg, 256, 0, stream>>>(hbf, wt + 2 * 262144, b2a, t1, N,
                                                    nwg, nullptr, nullptr);
  gemm_kernel<false, true><<<nwg, 256, 0, stream>>>(t1, wt + 3 * 262144, b2b, u, N,
                                                    nwg, sum2, sq2);
  bn_res_kernel<<<(n8 + 255) / 256, 256, 0, stream>>>(u, sum2, sq2, g2, be2,
                                                      x, (float*)d_out, n8, N);
}